// Round 2
// baseline (4711.171 us; speedup 1.0000x reference)
//
#include <hip/hip_runtime.h>
#include <cstdint>
#include <cstddef>

#define NB 256   // batch
#define NT 512   // time steps
#define ND 64    // input dim
#define NH 512   // hidden dim

typedef __attribute__((ext_vector_type(8))) short short8;
typedef __attribute__((ext_vector_type(4))) float f32x4;

__device__ __forceinline__ unsigned short f2bf(float f) {
  union { float f; uint32_t u; } v; v.f = f;
  uint32_t u = v.u;
  return (unsigned short)((u + 0x7FFFu + ((u >> 16) & 1u)) >> 16);  // RNE
}
__device__ __forceinline__ float bf2f(unsigned short b) {
  union { uint32_t u; float f; } v; v.u = ((uint32_t)b) << 16;
  return v.f;
}
__device__ __forceinline__ void split8(const float* v, short8& hi, short8& lo) {
#pragma unroll
  for (int e = 0; e < 8; ++e) {
    unsigned short hb = f2bf(v[e]);
    hi[e] = (short)hb;
    lo[e] = (short)f2bf(v[e] - bf2f(hb));
  }
}

// Per-call init: out = b_ho, zero h buffer 0 (both planes), zero sync counters.
__global__ void init_kernel(const float* __restrict__ bho, float* __restrict__ out,
                            unsigned int* __restrict__ hzero, unsigned int* __restrict__ cnt) {
  int i = blockIdx.x * 256 + threadIdx.x;
  if (i < NB * NT) out[i] = bho[0];
  if (i < (2 * NB * NH * 2) / 4) hzero[i] = 0u;   // 2 planes of u16 viewed as u32
  if (i < 16 * 32) cnt[i] = 0u;
}

// Persistent RNN: 256 blocks x 1 wave. Block = (bg, slice):
//   bg    = 16 batch rows (16 bgs), slice = 32 hidden cols (16 slices).
// W_hh/W_ih slice stationary in VGPRs as split-bf16 MFMA B-fragments.
// Per-bg 16-block flag sync per timestep (cumulative counter, release/acquire).
__global__ __launch_bounds__(64, 1) void rnn_persist(
    const float* __restrict__ x, const float* __restrict__ wih,
    const float* __restrict__ whh, const float* __restrict__ bih,
    const float* __restrict__ bhh, const float* __restrict__ who,
    unsigned short* __restrict__ hbuf,   // [2][2 planes][NB*NH] u16
    unsigned int* __restrict__ cnt,      // [16][32] u32 (128B stride per bg)
    float* __restrict__ out)
{
  const int bid  = blockIdx.x;
  // bg grouped so the 16 blocks of a bg land on the same XCD under round-robin
  const int bg   = ((bid & 7) << 1) | (bid >> 7);   // 0..15
  const int sl   = (bid >> 3) & 15;                 // 0..15
  const int lane = threadIdx.x;                     // 0..63
  const int lm   = lane & 15;
  const int lg   = lane >> 4;                       // 0..3
  const int lkb  = lg * 8;                          // k elem offset in 32-tile
  const int bm   = bg * 16;
  const int n0   = sl * 32;

  // ---- prologue: stationary weights ----
  short8 wh_hi[2][16], wh_lo[2][16];   // W_hh B-frags: [ntile][ktile], 256 VGPR
  short8 wx_hi[2][2],  wx_lo[2][2];    // W_ih B-frags
  float  bv[2], wov[2];
#pragma unroll
  for (int nt = 0; nt < 2; ++nt) {
    const int n = n0 + nt * 16 + lm;
    bv[nt]  = bih[n] + bhh[n];
    wov[nt] = who[n];
#pragma unroll
    for (int kt = 0; kt < 16; ++kt) {
      float v[8];
      const float* p = whh + (size_t)n * NH + kt * 32 + lkb;
      *(f32x4*)&v[0] = *(const f32x4*)p;
      *(f32x4*)&v[4] = *(const f32x4*)(p + 4);
      split8(v, wh_hi[nt][kt], wh_lo[nt][kt]);
    }
#pragma unroll
    for (int kt = 0; kt < 2; ++kt) {
      float v[8];
      const float* p = wih + (size_t)n * ND + kt * 32 + lkb;
      *(f32x4*)&v[0] = *(const f32x4*)p;
      *(f32x4*)&v[4] = *(const f32x4*)(p + 4);
      split8(v, wx_hi[nt][kt], wx_lo[nt][kt]);
    }
  }

  unsigned int* myc = cnt + bg * 32;

  for (int t = 0; t < NT; ++t) {
    const unsigned short* ph_hi = hbuf + (size_t)(t & 1) * (2 * NB * NH);
    const unsigned short* ph_lo = ph_hi + (size_t)NB * NH;
    unsigned short* nx_hi = hbuf + (size_t)((t + 1) & 1) * (2 * NB * NH);
    unsigned short* nx_lo = nx_hi + (size_t)NB * NH;

    f32x4 acc[2][3];
#pragma unroll
    for (int nt = 0; nt < 2; ++nt)
#pragma unroll
      for (int s = 0; s < 3; ++s) acc[nt][s] = (f32x4){0.f, 0.f, 0.f, 0.f};

    // x_t A-frags (fp32 -> split bf16 in-register)
    short8 ax_hi[2], ax_lo[2];
#pragma unroll
    for (int xt = 0; xt < 2; ++xt) {
      float v[8];
      const float* p = x + ((size_t)(bm + lm) * NT + t) * ND + xt * 32 + lkb;
      *(f32x4*)&v[0] = *(const f32x4*)p;
      *(f32x4*)&v[4] = *(const f32x4*)(p + 4);
      split8(v, ax_hi[xt], ax_lo[xt]);
    }

    // main K loop over h_prev (direct global->reg A-frags; B stationary)
    const unsigned short* arow_hi = ph_hi + (size_t)(bm + lm) * NH;
    const unsigned short* arow_lo = ph_lo + (size_t)(bm + lm) * NH;
#pragma unroll
    for (int kt = 0; kt < 16; ++kt) {
      short8 ah = *(const short8*)(arow_hi + kt * 32 + lkb);
      short8 al = *(const short8*)(arow_lo + kt * 32 + lkb);
#pragma unroll
      for (int nt = 0; nt < 2; ++nt) {
        acc[nt][0] = __builtin_amdgcn_mfma_f32_16x16x32_bf16(ah, wh_hi[nt][kt], acc[nt][0], 0, 0, 0);
        acc[nt][1] = __builtin_amdgcn_mfma_f32_16x16x32_bf16(ah, wh_lo[nt][kt], acc[nt][1], 0, 0, 0);
        acc[nt][2] = __builtin_amdgcn_mfma_f32_16x16x32_bf16(al, wh_hi[nt][kt], acc[nt][2], 0, 0, 0);
      }
    }
#pragma unroll
    for (int xt = 0; xt < 2; ++xt)
#pragma unroll
      for (int nt = 0; nt < 2; ++nt) {
        acc[nt][0] = __builtin_amdgcn_mfma_f32_16x16x32_bf16(ax_hi[xt], wx_hi[nt][xt], acc[nt][0], 0, 0, 0);
        acc[nt][1] = __builtin_amdgcn_mfma_f32_16x16x32_bf16(ax_hi[xt], wx_lo[nt][xt], acc[nt][1], 0, 0, 0);
        acc[nt][2] = __builtin_amdgcn_mfma_f32_16x16x32_bf16(ax_lo[xt], wx_hi[nt][xt], acc[nt][2], 0, 0, 0);
      }

    // epilogue: tanh, split-store h_next, fused out-projection partial
    float po[4];
#pragma unroll
    for (int r = 0; r < 4; ++r) po[r] = 0.f;
#pragma unroll
    for (int nt = 0; nt < 2; ++nt) {
#pragma unroll
      for (int r = 0; r < 4; ++r) {
        float pre = acc[nt][0][r] + acc[nt][1][r] + acc[nt][2][r] + bv[nt];
        float hv  = tanhf(pre);
        const int m = lg * 4 + r;
        const size_t idx = (size_t)(bm + m) * NH + n0 + nt * 16 + lm;
        unsigned short hb = f2bf(hv);
        nx_hi[idx] = hb;
        nx_lo[idx] = f2bf(hv - bf2f(hb));
        po[r] += hv * wov[nt];
      }
    }
#pragma unroll
    for (int s = 1; s < 16; s <<= 1)
#pragma unroll
      for (int r = 0; r < 4; ++r) po[r] += __shfl_xor(po[r], s, 64);
    if (lm == 0) {
#pragma unroll
      for (int r = 0; r < 4; ++r)
        atomicAdd(&out[(size_t)(bm + lg * 4 + r) * NT + t], po[r]);
    }

    // arrive (release: orders this wave's h stores) + wait for the 15 peers
    if (lane == 0)
      __hip_atomic_fetch_add(myc, 1u, __ATOMIC_RELEASE, __HIP_MEMORY_SCOPE_AGENT);
    const unsigned int target = 16u * (unsigned)(t + 1);
    if (lane == 0) {
      while (__hip_atomic_load(myc, __ATOMIC_RELAXED, __HIP_MEMORY_SCOPE_AGENT) < target)
        __builtin_amdgcn_s_sleep(1);
      (void)__hip_atomic_load(myc, __ATOMIC_ACQUIRE, __HIP_MEMORY_SCOPE_AGENT);
    }
    // wave lockstep: masked-off lanes cannot run ahead of lane 0's spin
  }
}

extern "C" void kernel_launch(void* const* d_in, const int* in_sizes, int n_in,
                              void* d_out, int out_size, void* d_ws, size_t ws_size,
                              hipStream_t stream) {
  const float* x   = (const float*)d_in[0];
  const float* wih = (const float*)d_in[1];
  const float* whh = (const float*)d_in[2];
  const float* bih = (const float*)d_in[3];
  const float* bhh = (const float*)d_in[4];
  const float* who = (const float*)d_in[5];
  const float* bho = (const float*)d_in[6];
  float* out = (float*)d_out;

  // ws layout: hbuf[2][2 planes][NB*NH] u16 (1 MB), then cnt[16*32] u32
  unsigned short* hbuf = (unsigned short*)d_ws;
  unsigned int* cnt = (unsigned int*)(hbuf + (size_t)2 * 2 * NB * NH);

  init_kernel<<<(NB * NT + 255) / 256, 256, 0, stream>>>(
      bho, out, (unsigned int*)hbuf, cnt);

  rnn_persist<<<256, 64, 0, stream>>>(x, wih, whh, bih, bhh, who, hbuf, cnt, out);
}